// Round 3
// baseline (52.329 us; speedup 1.0000x reference)
//
#include <hip/hip_runtime.h>

// CLF-QP batched solver. 8 lanes cooperate per state-row (ADIM=32, float4 per
// lane) so global loads and stores are perfectly coalesced (lane l <-> 16B at
// base+l*16) with no LDS round-trip. Row reductions are 3-step __shfl_xor
// butterflies within the 8-lane group (bitwise identical in all lanes, so the
// group never diverges). Clip-binding detection via one __ballot.
//
// Fast path: for nu in [0,LAM], clip(+-5) on u=-0.5*nu*a binds only if
// 0.5*LAM*|a_i| > 5; when it never binds g(nu)=b-0.5*nu*S is linear and the
// reference's bisection + implicit Newton step collapses exactly to nu=2b/S.
// Cold fallback replicates the full 60-iter bisection + Newton group-wide.

#define ADIM 32
#define BLK  256
static constexpr float LAMP = 1.0f;
static constexpr float CEXP = 1.0f;
static constexpr float LBND = -5.0f;
static constexpr float UBND = 5.0f;

__device__ __forceinline__ float clipu(float x) {
    return fminf(fmaxf(x, LBND), UBND);
}

__device__ __forceinline__ float grp_sum8(float v) {
    v += __shfl_xor(v, 1);
    v += __shfl_xor(v, 2);
    v += __shfl_xor(v, 4);
    return v;   // bitwise-identical across the 8-lane group
}

__global__ __launch_bounds__(BLK) void clfqp_kernel(
    const float* __restrict__ LfV,
    const float* __restrict__ Lg,
    const float* __restrict__ V,
    float* __restrict__ out,   // [n*ADIM] u, then [n] r
    int n)
{
    const int tid  = blockIdx.x * BLK + threadIdx.x;
    const int row  = tid >> 3;            // 8 lanes per row
    const int sub  = threadIdx.x & 7;     // which float4 of the row
    const int lane = threadIdx.x & 63;

    // __ballot must be wave-collective; compute predicate before any exit.
    float4 va = make_float4(0.f, 0.f, 0.f, 0.f);
    const bool active = row < n;
    if (active)
        va = reinterpret_cast<const float4*>(Lg)[(size_t)row * 8 + sub];

    bool clip_any = (fabsf(0.5f * LAMP * va.x) > UBND) |
                    (fabsf(0.5f * LAMP * va.y) > UBND) |
                    (fabsf(0.5f * LAMP * va.z) > UBND) |
                    (fabsf(0.5f * LAMP * va.w) > UBND);
    unsigned long long bal = __ballot(clip_any);
    if (!active) return;

    const bool cold = ((bal >> (lane & ~7)) & 0xffull) != 0ull;

    float b = LfV[row] + CEXP * V[row];

    // per-lane partials over 4 elements
    float Sp = 0.0f, gp = 0.0f;
    {
        Sp = fmaf(va.x, va.x, Sp); gp = fmaf(va.x, clipu(-0.5f * LAMP * va.x), gp);
        Sp = fmaf(va.y, va.y, Sp); gp = fmaf(va.y, clipu(-0.5f * LAMP * va.y), gp);
        Sp = fmaf(va.z, va.z, Sp); gp = fmaf(va.z, clipu(-0.5f * LAMP * va.z), gp);
        Sp = fmaf(va.w, va.w, Sp); gp = fmaf(va.w, clipu(-0.5f * LAMP * va.w), gp);
    }
    const float S    = grp_sum8(Sp);
    const float glam = b + grp_sum8(gp);

    float nu, r;
    if (b <= 0.0f) {
        nu = 0.0f; r = 0.0f;
    } else if (glam > 0.0f) {
        nu = LAMP; r = glam;
    } else {
        r = 0.0f;
        if (cold) {
            // faithful group-wide bisection + Newton (all 8 lanes together)
            float lo = 0.0f, hi = LAMP;
            #pragma unroll 1
            for (int it = 0; it < 60; ++it) {
                float mid = 0.5f * (lo + hi);
                float gpart = 0.0f;
                gpart = fmaf(va.x, clipu(-0.5f * mid * va.x), gpart);
                gpart = fmaf(va.y, clipu(-0.5f * mid * va.y), gpart);
                gpart = fmaf(va.z, clipu(-0.5f * mid * va.z), gpart);
                gpart = fmaf(va.w, clipu(-0.5f * mid * va.w), gpart);
                float g = b + grp_sum8(gpart);
                if (g > 0.0f) lo = mid; else hi = mid;
            }
            float nu0 = 0.5f * (lo + hi);
            float g0p = 0.0f, dgp = 0.0f;
            {
                float u0;
                u0 = clipu(-0.5f * nu0 * va.x); g0p = fmaf(va.x, u0, g0p);
                if (u0 > LBND && u0 < UBND) dgp = fmaf(va.x, va.x, dgp);
                u0 = clipu(-0.5f * nu0 * va.y); g0p = fmaf(va.y, u0, g0p);
                if (u0 > LBND && u0 < UBND) dgp = fmaf(va.y, va.y, dgp);
                u0 = clipu(-0.5f * nu0 * va.z); g0p = fmaf(va.z, u0, g0p);
                if (u0 > LBND && u0 < UBND) dgp = fmaf(va.z, va.z, dgp);
                u0 = clipu(-0.5f * nu0 * va.w); g0p = fmaf(va.w, u0, g0p);
                if (u0 > LBND && u0 < UBND) dgp = fmaf(va.w, va.w, dgp);
            }
            float g0 = b + grp_sum8(g0p);
            float dg = -0.5f * grp_sum8(dgp);
            if (!(dg < 0.0f)) dg = -1.0f;
            nu = nu0 - g0 / dg;
        } else {
            nu = 2.0f * b / S;   // linear g: Newton collapses to closed form
        }
    }

    // coalesced store of u (lane l -> 16B at row-block base + l*16)
    float4 u;
    u.x = clipu(-0.5f * nu * va.x);
    u.y = clipu(-0.5f * nu * va.y);
    u.z = clipu(-0.5f * nu * va.z);
    u.w = clipu(-0.5f * nu * va.w);
    reinterpret_cast<float4*>(out)[(size_t)row * 8 + sub] = u;

    if (sub == 0) out[(size_t)n * ADIM + row] = r;
}

extern "C" void kernel_launch(void* const* d_in, const int* in_sizes, int n_in,
                              void* d_out, int out_size, void* d_ws, size_t ws_size,
                              hipStream_t stream) {
    const float* LfV = (const float*)d_in[0];
    const float* Lg  = (const float*)d_in[1];
    const float* V   = (const float*)d_in[2];
    float* out = (float*)d_out;
    int n = in_sizes[0];

    long long threads = (long long)n * 8;            // 8 lanes per row
    int grid = (int)((threads + BLK - 1) / BLK);
    clfqp_kernel<<<grid, BLK, 0, stream>>>(LfV, Lg, V, out, n);
}

// Round 5
// 45.655 us; speedup vs baseline: 1.1462x; 1.1462x over previous
//
#include <hip/hip_runtime.h>

// CLF-QP batched solver. 8 lanes cooperate per state-row (ADIM=32, float4 per
// lane): global loads/stores perfectly coalesced, no LDS. Row reductions are
// 3-step __shfl_xor butterflies in the 8-lane group. Output stores are
// NON-TEMPORAL: outputs are never re-read by the kernel, and cacheable writes
// (135MB) were evicting the 137MB input set from the 256MB L3 every replay
// (observed FETCH_SIZE 70MB). Streaming the writes keeps inputs L3-resident.
// NOTE: __builtin_nontemporal_store needs a native ext_vector type, not HIP's
// float4 class -- hence f32x4 below.
//
// Fast path math: for nu in [0,LAM], clip(+-5) on u=-0.5*nu*a binds only if
// 0.5*LAM*|a_i| > 5; when it never binds g(nu)=b-0.5*nu*S is linear and the
// reference's bisection + implicit Newton step collapses exactly to nu=2b/S.
// Cold fallback replicates the full 60-iter bisection + Newton group-wide.

#define ADIM 32
#define BLK  256
static constexpr float LAMP = 1.0f;
static constexpr float CEXP = 1.0f;
static constexpr float LBND = -5.0f;
static constexpr float UBND = 5.0f;

typedef float f32x4 __attribute__((ext_vector_type(4)));

__device__ __forceinline__ float clipu(float x) {
    return fminf(fmaxf(x, LBND), UBND);
}

__device__ __forceinline__ float grp_sum8(float v) {
    v += __shfl_xor(v, 1);
    v += __shfl_xor(v, 2);
    v += __shfl_xor(v, 4);
    return v;   // bitwise-identical across the 8-lane group
}

__global__ __launch_bounds__(BLK) void clfqp_kernel(
    const float* __restrict__ LfV,
    const float* __restrict__ Lg,
    const float* __restrict__ V,
    float* __restrict__ out,   // [n*ADIM] u, then [n] r
    int n)
{
    const int tid  = blockIdx.x * BLK + threadIdx.x;
    const int row  = tid >> 3;            // 8 lanes per row
    const int sub  = threadIdx.x & 7;     // which float4 of the row
    const int lane = threadIdx.x & 63;

    // __ballot must be wave-collective; compute predicate before any exit.
    f32x4 va = {0.f, 0.f, 0.f, 0.f};
    const bool active = row < n;
    if (active)
        va = reinterpret_cast<const f32x4*>(Lg)[(size_t)row * 8 + sub];

    bool clip_any = (fabsf(0.5f * LAMP * va.x) > UBND) |
                    (fabsf(0.5f * LAMP * va.y) > UBND) |
                    (fabsf(0.5f * LAMP * va.z) > UBND) |
                    (fabsf(0.5f * LAMP * va.w) > UBND);
    unsigned long long bal = __ballot(clip_any);
    if (!active) return;

    const bool cold = ((bal >> (lane & ~7)) & 0xffull) != 0ull;

    float b = LfV[row] + CEXP * V[row];

    // per-lane partials over 4 elements
    float Sp = 0.0f, gp = 0.0f;
    Sp = fmaf(va.x, va.x, Sp); gp = fmaf(va.x, clipu(-0.5f * LAMP * va.x), gp);
    Sp = fmaf(va.y, va.y, Sp); gp = fmaf(va.y, clipu(-0.5f * LAMP * va.y), gp);
    Sp = fmaf(va.z, va.z, Sp); gp = fmaf(va.z, clipu(-0.5f * LAMP * va.z), gp);
    Sp = fmaf(va.w, va.w, Sp); gp = fmaf(va.w, clipu(-0.5f * LAMP * va.w), gp);

    const float S    = grp_sum8(Sp);
    const float glam = b + grp_sum8(gp);

    float nu, r;
    if (b <= 0.0f) {
        nu = 0.0f; r = 0.0f;
    } else if (glam > 0.0f) {
        nu = LAMP; r = glam;
    } else {
        r = 0.0f;
        if (cold) {
            // faithful group-wide bisection + Newton (all 8 lanes together)
            float lo = 0.0f, hi = LAMP;
            #pragma unroll 1
            for (int it = 0; it < 60; ++it) {
                float mid = 0.5f * (lo + hi);
                float gpart = 0.0f;
                gpart = fmaf(va.x, clipu(-0.5f * mid * va.x), gpart);
                gpart = fmaf(va.y, clipu(-0.5f * mid * va.y), gpart);
                gpart = fmaf(va.z, clipu(-0.5f * mid * va.z), gpart);
                gpart = fmaf(va.w, clipu(-0.5f * mid * va.w), gpart);
                float g = b + grp_sum8(gpart);
                if (g > 0.0f) lo = mid; else hi = mid;
            }
            float nu0 = 0.5f * (lo + hi);
            float g0p = 0.0f, dgp = 0.0f;
            {
                float u0;
                u0 = clipu(-0.5f * nu0 * va.x); g0p = fmaf(va.x, u0, g0p);
                if (u0 > LBND && u0 < UBND) dgp = fmaf(va.x, va.x, dgp);
                u0 = clipu(-0.5f * nu0 * va.y); g0p = fmaf(va.y, u0, g0p);
                if (u0 > LBND && u0 < UBND) dgp = fmaf(va.y, va.y, dgp);
                u0 = clipu(-0.5f * nu0 * va.z); g0p = fmaf(va.z, u0, g0p);
                if (u0 > LBND && u0 < UBND) dgp = fmaf(va.z, va.z, dgp);
                u0 = clipu(-0.5f * nu0 * va.w); g0p = fmaf(va.w, u0, g0p);
                if (u0 > LBND && u0 < UBND) dgp = fmaf(va.w, va.w, dgp);
            }
            float g0 = b + grp_sum8(g0p);
            float dg = -0.5f * grp_sum8(dgp);
            if (!(dg < 0.0f)) dg = -1.0f;
            nu = nu0 - g0 / dg;
        } else {
            nu = 2.0f * b / S;   // linear g: Newton collapses to closed form
        }
    }

    // coalesced NON-TEMPORAL store of u (outputs never re-read -> don't cache)
    f32x4 u;
    u.x = clipu(-0.5f * nu * va.x);
    u.y = clipu(-0.5f * nu * va.y);
    u.z = clipu(-0.5f * nu * va.z);
    u.w = clipu(-0.5f * nu * va.w);
    __builtin_nontemporal_store(u, reinterpret_cast<f32x4*>(out) + (size_t)row * 8 + sub);

    if (sub == 0)
        __builtin_nontemporal_store(r, out + (size_t)n * ADIM + row);
}

extern "C" void kernel_launch(void* const* d_in, const int* in_sizes, int n_in,
                              void* d_out, int out_size, void* d_ws, size_t ws_size,
                              hipStream_t stream) {
    const float* LfV = (const float*)d_in[0];
    const float* Lg  = (const float*)d_in[1];
    const float* V   = (const float*)d_in[2];
    float* out = (float*)d_out;
    int n = in_sizes[0];

    long long threads = (long long)n * 8;            // 8 lanes per row
    int grid = (int)((threads + BLK - 1) / BLK);
    clfqp_kernel<<<grid, BLK, 0, stream>>>(LfV, Lg, V, out, n);
}